// Round 2
// baseline (325.732 us; speedup 1.0000x reference)
//
#include <hip/hip_runtime.h>
#include <hip/hip_cooperative_groups.h>
#include <math.h>

namespace cg = cooperative_groups;

#define B_  8
#define S_  2048
#define H_  256
#define HK_ 128
#define P_  64
#define NQ_ 20
#define M_  (B_*S_)          // 16384 rows
// per-batch accumulator: G[20][64]@0, E[20][64]@1280, T[64]@2560, W[20]@2624, n[20]@2644, pad->2688
#define ACC_STRIDE 2688
#define NREP 4               // replicated global accumulators: spreads atomic contention 4x

// ws layout (float units)
#define WS_ACC   0                                // NREP*8*2688 = 86016 floats
#define WS_WT    (NREP*B_*ACC_STRIDE)             // bf16 frags: 65536 shorts = 32768 floats

typedef __attribute__((ext_vector_type(8))) short bf16x8;
typedef __attribute__((ext_vector_type(4))) float f32x4;

// ---------------------------------------------------------------------------
// Single cooperative kernel, 512 blocks x 256 threads (2 blocks/CU co-resident).
//
// Pre-phase : blocks 0..31 scatter w1 (RNE->bf16) into MFMA B-fragment order
//             wtf[mlp][kt(8)][nt(8)][lane(64)][j(8)] and zero ws_acc replicas.
//             ALL blocks meanwhile load fx + do the A hi/lo bf16 split into
//             registers (independent of wtf -> hides prep latency).
//             grid.sync().
// Phase A   : dual-MLP bf16 MFMA (16x16x32, 2-term A-split), B-frags straight
//             from global (L2 broadcast). sim/conf -> LDS only.
// Phase B   : bucketed sums via fire-and-forget LDS atomics, then skip-zero
//             global atomic flush into one of NREP per-batch replicas.
//             __threadfence() + grid.sync().
// Phase C   : out = c*px + (1-c)*((T-G_q+E_q)/denom_q) for this block's own
//             32 rows (conf/q from LDS, px L2-warm, replicas L2-hot).
// ---------------------------------------------------------------------------
__launch_bounds__(256, 2)
__global__ void fused_kernel(const float* __restrict__ fx, const float* __restrict__ px,
                             const float* __restrict__ sw1, const float* __restrict__ sb1,
                             const float* __restrict__ sw2, const float* __restrict__ sb2,
                             const float* __restrict__ cw1, const float* __restrict__ cb1,
                             const float* __restrict__ cw2, const float* __restrict__ cb2,
                             const int* __restrict__ questions, short* __restrict__ wtf,
                             float* __restrict__ ws_acc, float* __restrict__ out)
{
    cg::grid_group grid = cg::this_grid();
    __shared__ float accs[ACC_STRIDE];
    __shared__ float sim_l[32];
    __shared__ float conf_l[32];
    __shared__ int   q_l[32];

    const int tid = threadIdx.x;
    const int bid = blockIdx.x;

    // ---- pre-phase: weight prep (blocks 0..31) -----------------------------
    if (bid < 32) {
        const int t = bid * 256 + tid;                 // 0..8191
        const int pl = t & 63, pnt = (t >> 6) & 7, pkt = (t >> 9) & 7, pmlp = t >> 12;
        const int pcol = pl & 15, pquad = pl >> 4;
        const int n = pnt * 16 + pcol;
        const float* w1 = pmlp ? cw1 : sw1;
        short frag[8];
        #pragma unroll
        for (int j = 0; j < 8; ++j) {
            int k = pkt * 32 + pquad * 8 + j;
            union { float f; unsigned u; } c; c.f = w1[k * HK_ + n];
            frag[j] = (short)((c.u + 0x7FFF + ((c.u >> 16) & 1)) >> 16);   // RNE
        }
        *(uint4*)(wtf + (size_t)t * 8) = *(const uint4*)frag;
        for (int s = t; s < NREP * B_ * ACC_STRIDE; s += 8192) ws_acc[s] = 0.f;
    }

    // zero block-local accumulators (consumed after the __syncthreads in B)
    for (int s = tid; s < ACC_STRIDE; s += 256) accs[s] = 0.f;

    // ---- A-operand load + hi/lo bf16 split (independent of wtf) ------------
    const int w    = tid >> 6, l = tid & 63;
    const int col  = l & 15, quad = l >> 4;
    const int mlp  = w >> 1, mt = w & 1;
    const int row  = bid * 32 + mt * 16 + col;         // A-operand m = lane&15
    const int row0 = bid * 32;

    bf16x8 ahi[8], alo[8];
    {
        const float* fxrow = fx + (size_t)row * H_;
        #pragma unroll
        for (int kt = 0; kt < 8; ++kt) {
            float4 a0 = *(const float4*)(fxrow + kt * 32 + quad * 8);
            float4 a1 = *(const float4*)(fxrow + kt * 32 + quad * 8 + 4);
            float af[8] = {a0.x, a0.y, a0.z, a0.w, a1.x, a1.y, a1.z, a1.w};
            #pragma unroll
            for (int i = 0; i < 8; ++i) {
                union { float f; unsigned u; } c; c.f = af[i];
                unsigned hi = c.u >> 16;                       // truncate: lo holds residual
                ahi[kt][i] = (short)hi;
                union { float f; unsigned u; } h2; h2.u = hi << 16;
                union { float f; unsigned u; } c2; c2.f = af[i] - h2.f;
                alo[kt][i] = (short)(c2.u >> 16);
            }
        }
    }

    __threadfence();
    grid.sync();                                       // wtf + ws_acc zero visible

    // ---- phase A: MFMA ------------------------------------------------------
    f32x4 acc[8];
    #pragma unroll
    for (int nt = 0; nt < 8; ++nt) acc[nt] = (f32x4){0.f, 0.f, 0.f, 0.f};

    const short* wf = wtf + (size_t)mlp * 32768 + (size_t)l * 8;
    #pragma unroll
    for (int kt = 0; kt < 8; ++kt) {
        const short* base = wf + (size_t)kt * 4096;
        #pragma unroll
        for (int nt = 0; nt < 8; ++nt) {
            bf16x8 bf = *(const bf16x8*)(base + nt * 512);
            acc[nt] = __builtin_amdgcn_mfma_f32_16x16x32_bf16(ahi[kt], bf, acc[nt], 0, 0, 0);
            acc[nt] = __builtin_amdgcn_mfma_f32_16x16x32_bf16(alo[kt], bf, acc[nt], 0, 0, 0);
        }
    }

    // fp32 layer-2 epilogue -> sim/conf in LDS
    {
        const float* b1 = mlp ? cb1 : sb1;
        const float* w2 = mlp ? cw2 : sw2;
        const float  b2v = mlp ? cb2[0] : sb2[0];
        float p[4] = {0.f, 0.f, 0.f, 0.f};
        #pragma unroll
        for (int nt = 0; nt < 8; ++nt) {
            float b1c = b1[nt * 16 + col];
            float w2c = w2[nt * 16 + col];
            #pragma unroll
            for (int j = 0; j < 4; ++j)
                p[j] += fmaxf(acc[nt][j] + b1c, 0.f) * w2c;
        }
        #pragma unroll
        for (int off = 8; off >= 1; off >>= 1)
            #pragma unroll
            for (int j = 0; j < 4; ++j) p[j] += __shfl_down(p[j], off, 16);

        if (col == 0) {
            #pragma unroll
            for (int j = 0; j < 4; ++j) {
                int rloc = mt * 16 + quad * 4 + j;             // D row = quad*4+reg
                float v = p[j] + b2v;
                if (mlp == 0) sim_l[rloc]  = v;
                else          conf_l[rloc] = 1.0f / (1.0f + expf(-v));
            }
        }
    }
    __syncthreads();   // accs zeroed + sim_l/conf_l written

    // ---- phase B: bucketed sums for this block's 32 rows --------------------
    float Treg = 0.f;
    #pragma unroll
    for (int t = 0; t < 8; ++t) {
        const int il = w + 4 * t;
        const int i  = row0 + il;
        const int qi = questions[i];                  // wave-uniform -> scalar broadcast
        const float e = expf(sim_l[il]);
        const float v = px[(size_t)i * P_ + l];       // coalesced 256B per wave
        Treg += v;
        atomicAdd(&accs[qi * 64 + l], v);             // ds_add_f32, fire-and-forget
        atomicAdd(&accs[(20 + qi) * 64 + l], e * v);
        if (l == 0) {
            q_l[il] = qi;
            atomicAdd(&accs[2624 + qi], e);           // W_q (denominator exp-sum)
            atomicAdd(&accs[2644 + qi], 1.0f);        // n_q (group size)
        }
    }
    atomicAdd(&accs[2560 + l], Treg);                 // T
    __syncthreads();

    // skip-zero flush: adding 0.0 is a no-op, so skipping is always correct
    const int b   = bid >> 6;                         // 64 blocks per batch
    const int rep = bid & (NREP - 1);
    {
        float* dst = ws_acc + (size_t)(b * NREP + rep) * ACC_STRIDE;
        for (int s = tid; s < ACC_STRIDE; s += 256) {
            const float vv = accs[s];
            if (vv != 0.f) atomicAdd(dst + s, vv);
        }
    }

    __threadfence();
    grid.sync();                                      // all replica flushes visible

    // ---- phase C: output for this block's own 32 rows -----------------------
    const int p4 = tid & 15;
    #pragma unroll
    for (int half = 0; half < 2; ++half) {
        const int il = (tid >> 4) + half * 16;        // 0..31
        const int i  = row0 + il;
        const float c = conf_l[il];
        const int   q = q_l[il];

        float Tx=0.f,Ty=0.f,Tz=0.f,Tw=0.f;
        float Gx=0.f,Gy=0.f,Gz=0.f,Gw=0.f;
        float Ex=0.f,Ey=0.f,Ez=0.f,Ew=0.f;
        float Wq=0.f, nq=0.f;
        #pragma unroll
        for (int rp = 0; rp < NREP; ++rp) {
            const float* a = ws_acc + (size_t)(b * NREP + rp) * ACC_STRIDE;
            const float4 t4 = *(const float4*)(a + 2560 + p4 * 4);
            const float4 g4 = *(const float4*)(a + q * 64 + p4 * 4);
            const float4 e4 = *(const float4*)(a + (20 + q) * 64 + p4 * 4);
            Tx += t4.x; Ty += t4.y; Tz += t4.z; Tw += t4.w;
            Gx += g4.x; Gy += g4.y; Gz += g4.z; Gw += g4.w;
            Ex += e4.x; Ey += e4.y; Ez += e4.z; Ew += e4.w;
            Wq += a[2624 + q]; nq += a[2644 + q];
        }
        const float denom = ((float)S_ - nq) + Wq;
        const float inv = 1.0f / denom;
        const float4 pv = ((const float4*)px)[(size_t)i * 16 + p4];
        const float om = 1.0f - c;
        float4 o;
        o.x = c * pv.x + om * ((Tx - Gx + Ex) * inv);
        o.y = c * pv.y + om * ((Ty - Gy + Ey) * inv);
        o.z = c * pv.z + om * ((Tz - Gz + Ez) * inv);
        o.w = c * pv.w + om * ((Tw - Gw + Ew) * inv);
        ((float4*)out)[(size_t)i * 16 + p4] = o;
    }
}

// ---------------------------------------------------------------------------
extern "C" void kernel_launch(void* const* d_in, const int* in_sizes, int n_in,
                              void* d_out, int out_size, void* d_ws, size_t ws_size,
                              hipStream_t stream) {
    const float* fx  = (const float*)d_in[0];
    const float* px  = (const float*)d_in[1];
    const float* sw1 = (const float*)d_in[2];
    const float* sb1 = (const float*)d_in[3];
    const float* sw2 = (const float*)d_in[4];
    const float* sb2 = (const float*)d_in[5];
    const float* cw1 = (const float*)d_in[6];
    const float* cb1 = (const float*)d_in[7];
    const float* cw2 = (const float*)d_in[8];
    const float* cb2 = (const float*)d_in[9];
    const int* questions = (const int*)d_in[10];
    float* out = (float*)d_out;

    float* ws     = (float*)d_ws;
    float* ws_acc = ws + WS_ACC;
    short* wtf    = (short*)(ws + WS_WT);

    void* args[] = {
        (void*)&fx, (void*)&px, (void*)&sw1, (void*)&sb1, (void*)&sw2, (void*)&sb2,
        (void*)&cw1, (void*)&cb1, (void*)&cw2, (void*)&cb2,
        (void*)&questions, (void*)&wtf, (void*)&ws_acc, (void*)&out
    };
    hipLaunchCooperativeKernel((void*)fused_kernel, dim3(M_ / 32), dim3(256),
                               args, 0, stream);
}

// Round 3
// 117.087 us; speedup vs baseline: 2.7820x; 2.7820x over previous
//
#include <hip/hip_runtime.h>
#include <math.h>

#define B_  8
#define S_  2048
#define H_  256
#define HK_ 128
#define P_  64
#define NQ_ 20
#define M_  (B_*S_)          // 16384 rows
// per-batch accumulator: G[20][64]@0, E[20][64]@1280, T[64]@2560, W[20]@2624, n[20]@2644, pad->2688
#define ACC_STRIDE 2688
#define NREP 4               // replicated global accumulators: spreads atomic contention 4x

// ws layout (float units)
#define WS_SIM   0
#define WS_CONF  16384
#define WS_ACC   32768                            // NREP*8*2688 = 86016 floats
#define WS_WT    (32768 + NREP*B_*ACC_STRIDE)     // 118784; bf16 frags: 65536 shorts

typedef __attribute__((ext_vector_type(8))) short bf16x8;
typedef __attribute__((ext_vector_type(4))) float f32x4;

// ---------------------------------------------------------------------------
// Kernel 0: prep — round w1 (fp32 [k=256][n=128]) RNE to bf16 and scatter into
// MFMA B-fragment order wtf[mlp][kt(8)][nt(8)][lane(64)][j(8)]:
//   lane l -> col=l&15, quad=l>>4;  element j: B[k = kt*32+quad*8+j][n = nt*16+col]
// Also zeros the NREP replicated ws accumulator regions.
// ---------------------------------------------------------------------------
__global__ void prep_kernel(const float* __restrict__ sw1, const float* __restrict__ cw1,
                            short* __restrict__ wtf, float* __restrict__ ws_acc)
{
    const int t = blockIdx.x * 256 + threadIdx.x;      // 0..8191
    const int l = t & 63, nt = (t >> 6) & 7, kt = (t >> 9) & 7, mlp = t >> 12;
    const int col = l & 15, quad = l >> 4;
    const int n = nt * 16 + col;
    const float* w1 = mlp ? cw1 : sw1;
    short frag[8];
    #pragma unroll
    for (int j = 0; j < 8; ++j) {
        int k = kt * 32 + quad * 8 + j;
        union { float f; unsigned u; } c; c.f = w1[k * HK_ + n];
        frag[j] = (short)((c.u + 0x7FFF + ((c.u >> 16) & 1)) >> 16);   // RNE
    }
    *(uint4*)(wtf + (size_t)t * 8) = *(const uint4*)frag;
    for (int s = t; s < NREP * B_ * ACC_STRIDE; s += 8192) ws_acc[s] = 0.f;
}

// ---------------------------------------------------------------------------
// Kernel 1: dual MLP via bf16 MFMA (16x16x32), 2-term A-split (Ahi+Alo).
// NO LDS, no barriers: B-fragments loaded straight from global (L2-broadcast,
// fragment-ordered so each load is a fully coalesced 1KB wave read).
// Block = 4 waves; wave w: mlp=w>>1, row-tile mt=w&1 (32 rows/block).
// Fused fp32 layer-2 epilogue: relu(h+b1)·w2 + shfl reduce -> sim / sigmoid conf.
// [Identical to the 110.8 µs round-0 kernel — do not touch.]
// ---------------------------------------------------------------------------
__launch_bounds__(256)
__global__ void mlp_mfma_kernel(const float* __restrict__ fx, const short* __restrict__ wtf,
                                const float* __restrict__ sb1, const float* __restrict__ sw2,
                                const float* __restrict__ sb2, const float* __restrict__ cb1,
                                const float* __restrict__ cw2, const float* __restrict__ cb2,
                                float* __restrict__ sim, float* __restrict__ conf)
{
    const int tid  = threadIdx.x;
    const int w    = tid >> 6, l = tid & 63;
    const int col  = l & 15, quad = l >> 4;
    const int mlp  = w >> 1, mt = w & 1;
    const int row  = blockIdx.x * 32 + mt * 16 + col;  // A-operand m = lane&15

    f32x4 acc[8];
    #pragma unroll
    for (int nt = 0; nt < 8; ++nt) acc[nt] = (f32x4){0.f, 0.f, 0.f, 0.f};

    const float* fxrow = fx + (size_t)row * H_;
    const short* wf = wtf + (size_t)mlp * 32768 + (size_t)l * 8;

    #pragma unroll
    for (int kt = 0; kt < 8; ++kt) {
        float4 a0 = *(const float4*)(fxrow + kt * 32 + quad * 8);
        float4 a1 = *(const float4*)(fxrow + kt * 32 + quad * 8 + 4);
        float af[8] = {a0.x, a0.y, a0.z, a0.w, a1.x, a1.y, a1.z, a1.w};
        bf16x8 ahi, alo;
        #pragma unroll
        for (int i = 0; i < 8; ++i) {
            union { float f; unsigned u; } c; c.f = af[i];
            unsigned hi = c.u >> 16;                       // truncate: lo holds residual
            ahi[i] = (short)hi;
            union { float f; unsigned u; } h2; h2.u = hi << 16;
            union { float f; unsigned u; } c2; c2.f = af[i] - h2.f;
            alo[i] = (short)(c2.u >> 16);
        }
        const short* base = wf + (size_t)kt * 4096;
        #pragma unroll
        for (int nt = 0; nt < 8; ++nt) {
            bf16x8 bf = *(const bf16x8*)(base + nt * 512);
            acc[nt] = __builtin_amdgcn_mfma_f32_16x16x32_bf16(ahi, bf, acc[nt], 0, 0, 0);
            acc[nt] = __builtin_amdgcn_mfma_f32_16x16x32_bf16(alo, bf, acc[nt], 0, 0, 0);
        }
    }

    // fp32 layer-2 epilogue
    const float* b1 = mlp ? cb1 : sb1;
    const float* w2 = mlp ? cw2 : sw2;
    const float  b2v = mlp ? cb2[0] : sb2[0];
    float p[4] = {0.f, 0.f, 0.f, 0.f};
    #pragma unroll
    for (int nt = 0; nt < 8; ++nt) {
        float b1c = b1[nt * 16 + col];
        float w2c = w2[nt * 16 + col];
        #pragma unroll
        for (int j = 0; j < 4; ++j)
            p[j] += fmaxf(acc[nt][j] + b1c, 0.f) * w2c;
    }
    #pragma unroll
    for (int off = 8; off >= 1; off >>= 1)
        #pragma unroll
        for (int j = 0; j < 4; ++j) p[j] += __shfl_down(p[j], off, 16);

    if (col == 0) {
        #pragma unroll
        for (int j = 0; j < 4; ++j) {
            int r = blockIdx.x * 32 + mt * 16 + quad * 4 + j;   // D row = quad*4+reg
            float v = p[j] + b2v;
            if (mlp == 0) sim[r] = v;
            else          conf[r] = 1.0f / (1.0f + expf(-v));
        }
    }
}

// ---------------------------------------------------------------------------
// Kernel 2: bucketed sums over param_x + softmax-denominator stats.
// 512 blocks (2/CU), 32 rows each. Fire-and-forget LDS atomicAdd (ds_add_f32,
// no read-modify-write dependency chain), then skip-zero global atomic flush
// into one of NREP=4 per-batch replicas (contention spread 4x).
// ---------------------------------------------------------------------------
__launch_bounds__(256)
__global__ void accum_kernel(const float* __restrict__ sim, const int* __restrict__ questions,
                             const float* __restrict__ px, float* __restrict__ ws_acc)
{
    const int bid = blockIdx.x;           // 0..511; 64 blocks per batch
    const int tid = threadIdx.x;
    const int w = tid >> 6, l = tid & 63;
    __shared__ float accs[ACC_STRIDE];
    for (int s = tid; s < ACC_STRIDE; s += 256) accs[s] = 0.f;
    __syncthreads();

    const int row0 = bid * 32;
    float Treg = 0.f;
    #pragma unroll
    for (int t = 0; t < 8; ++t) {
        const int i  = row0 + w + 4 * t;
        const int qi = questions[i];                  // wave-uniform -> scalar broadcast
        const float e = expf(sim[i]);                 // wave-uniform VALU
        const float v = px[(size_t)i * P_ + l];       // coalesced 256B per wave
        Treg += v;
        atomicAdd(&accs[qi * 64 + l], v);             // ds_add_f32, fire-and-forget
        atomicAdd(&accs[(20 + qi) * 64 + l], e * v);
        if (l == 0) {
            atomicAdd(&accs[2624 + qi], e);           // W_q (denominator exp-sum)
            atomicAdd(&accs[2644 + qi], 1.0f);        // n_q (group size)
        }
    }
    atomicAdd(&accs[2560 + l], Treg);                 // T
    __syncthreads();

    // skip-zero flush: adding 0.0 is a no-op, so skipping is always correct
    const int b   = bid >> 6;
    const int rep = bid & (NREP - 1);
    float* dst = ws_acc + (size_t)(b * NREP + rep) * ACC_STRIDE;
    for (int s = tid; s < ACC_STRIDE; s += 256) {
        const float vv = accs[s];
        if (vv != 0.f) atomicAdd(dst + s, vv);
    }
}

// ---------------------------------------------------------------------------
// Kernel 3: out = c*px + (1-c) * ((T - G_q + E_q) / denom_q), float4 per thread.
// Sums the NREP accumulator replicas (344 KB total, L2-hot).
// denom_q = (S - n_q) + W_q.
// ---------------------------------------------------------------------------
__global__ void output_kernel(const float* __restrict__ px, const float* __restrict__ conf,
                              const int* __restrict__ questions, const float* __restrict__ ws_acc,
                              float* __restrict__ out)
{
    const int idx = blockIdx.x * 256 + threadIdx.x;  // float4 units, 262144 total
    const int row = idx >> 4;                        // b*S + s
    const int p4  = idx & 15;
    const int b   = row >> 11;                       // S = 2048
    const float c = conf[row];
    const int   q = questions[row];

    float Tx=0.f,Ty=0.f,Tz=0.f,Tw=0.f;
    float Gx=0.f,Gy=0.f,Gz=0.f,Gw=0.f;
    float Ex=0.f,Ey=0.f,Ez=0.f,Ew=0.f;
    float Wq=0.f, nq=0.f;
    #pragma unroll
    for (int rep = 0; rep < NREP; ++rep) {
        const float* a = ws_acc + (size_t)(b * NREP + rep) * ACC_STRIDE;
        const float4 t4 = *(const float4*)(a + 2560 + p4 * 4);
        const float4 g4 = *(const float4*)(a + q * 64 + p4 * 4);
        const float4 e4 = *(const float4*)(a + (20 + q) * 64 + p4 * 4);
        Tx += t4.x; Ty += t4.y; Tz += t4.z; Tw += t4.w;
        Gx += g4.x; Gy += g4.y; Gz += g4.z; Gw += g4.w;
        Ex += e4.x; Ey += e4.y; Ez += e4.z; Ew += e4.w;
        Wq += a[2624 + q]; nq += a[2644 + q];
    }
    const float denom = ((float)S_ - nq) + Wq;
    const float inv = 1.0f / denom;
    const float4 pv = ((const float4*)px)[idx];
    const float om = 1.0f - c;
    float4 o;
    o.x = c * pv.x + om * ((Tx - Gx + Ex) * inv);
    o.y = c * pv.y + om * ((Ty - Gy + Ey) * inv);
    o.z = c * pv.z + om * ((Tz - Gz + Ez) * inv);
    o.w = c * pv.w + om * ((Tw - Gw + Ew) * inv);
    ((float4*)out)[idx] = o;
}

// ---------------------------------------------------------------------------
extern "C" void kernel_launch(void* const* d_in, const int* in_sizes, int n_in,
                              void* d_out, int out_size, void* d_ws, size_t ws_size,
                              hipStream_t stream) {
    const float* fx  = (const float*)d_in[0];
    const float* px  = (const float*)d_in[1];
    const float* sw1 = (const float*)d_in[2];
    const float* sb1 = (const float*)d_in[3];
    const float* sw2 = (const float*)d_in[4];
    const float* sb2 = (const float*)d_in[5];
    const float* cw1 = (const float*)d_in[6];
    const float* cb1 = (const float*)d_in[7];
    const float* cw2 = (const float*)d_in[8];
    const float* cb2 = (const float*)d_in[9];
    const int* questions = (const int*)d_in[10];
    float* out = (float*)d_out;

    float* ws     = (float*)d_ws;
    float* sim    = ws + WS_SIM;
    float* conf   = ws + WS_CONF;
    float* ws_acc = ws + WS_ACC;
    short* wtf    = (short*)(ws + WS_WT);

    prep_kernel<<<32, 256, 0, stream>>>(sw1, cw1, wtf, ws_acc);
    mlp_mfma_kernel<<<M_ / 32, 256, 0, stream>>>(fx, wtf, sb1, sw2, sb2,
                                                 cb1, cw2, cb2, sim, conf);
    accum_kernel<<<512, 256, 0, stream>>>(sim, questions, px, ws_acc);
    output_kernel<<<(M_ * P_ / 4) / 256, 256, 0, stream>>>(px, conf, questions,
                                                           ws_acc, out);
}

// Round 4
// 110.022 us; speedup vs baseline: 2.9606x; 1.0642x over previous
//
#include <hip/hip_runtime.h>
#include <math.h>

#define B_  8
#define S_  2048
#define H_  256
#define HK_ 128
#define P_  64
#define NQ_ 20
#define M_  (B_*S_)          // 16384 rows
// per-batch accumulator: G[20][64]@0, E[20][64]@1280, T[64]@2560, W[20]@2624, n[20]@2644, pad->2688
#define ACC_STRIDE 2688

// ws layout (float units)
#define WS_SIM   0
#define WS_CONF  16384
#define WS_ACC   32768            // 8*2688 = 21504 floats
#define WS_WT    54272            // bf16 frags: 2*8*8*64*8 = 65536 shorts = 32768 float slots

typedef __attribute__((ext_vector_type(8))) short bf16x8;
typedef __attribute__((ext_vector_type(4))) float f32x4;

// ---------------------------------------------------------------------------
// Kernel 0: prep — round w1 (fp32 [k=256][n=128]) RNE to bf16 and scatter into
// MFMA B-fragment order wtf[mlp][kt(8)][nt(8)][lane(64)][j(8)]:
//   lane l -> col=l&15, quad=l>>4;  element j: B[k = kt*32+quad*8+j][n = nt*16+col]
// Also zeros the ws accumulator region. 8192 threads, each writes one 16B frag.
// ---------------------------------------------------------------------------
__global__ void prep_kernel(const float* __restrict__ sw1, const float* __restrict__ cw1,
                            short* __restrict__ wtf, float* __restrict__ ws_acc)
{
    const int t = blockIdx.x * 256 + threadIdx.x;      // 0..8191
    const int l = t & 63, nt = (t >> 6) & 7, kt = (t >> 9) & 7, mlp = t >> 12;
    const int col = l & 15, quad = l >> 4;
    const int n = nt * 16 + col;
    const float* w1 = mlp ? cw1 : sw1;
    short frag[8];
    #pragma unroll
    for (int j = 0; j < 8; ++j) {
        int k = kt * 32 + quad * 8 + j;
        union { float f; unsigned u; } c; c.f = w1[k * HK_ + n];
        frag[j] = (short)((c.u + 0x7FFF + ((c.u >> 16) & 1)) >> 16);   // RNE
    }
    *(uint4*)(wtf + (size_t)t * 8) = *(const uint4*)frag;
    for (int s = t; s < B_ * ACC_STRIDE; s += 8192) ws_acc[s] = 0.f;
}

// ---------------------------------------------------------------------------
// Kernel 1: dual MLP via bf16 MFMA (16x16x32), 2-term A-split (Ahi+Alo).
// NO LDS, no barriers: B-fragments loaded straight from global (L2-broadcast,
// fragment-ordered so each load is a fully coalesced 1KB wave read).
// Block = 4 waves; wave w: mlp=w>>1, row-tile mt=w&1 (32 rows/block).
// Fused fp32 layer-2 epilogue: relu(h+b1)·w2 + shfl reduce -> sim / sigmoid conf.
// ---------------------------------------------------------------------------
__launch_bounds__(256)
__global__ void mlp_mfma_kernel(const float* __restrict__ fx, const short* __restrict__ wtf,
                                const float* __restrict__ sb1, const float* __restrict__ sw2,
                                const float* __restrict__ sb2, const float* __restrict__ cb1,
                                const float* __restrict__ cw2, const float* __restrict__ cb2,
                                float* __restrict__ sim, float* __restrict__ conf)
{
    const int tid  = threadIdx.x;
    const int w    = tid >> 6, l = tid & 63;
    const int col  = l & 15, quad = l >> 4;
    const int mlp  = w >> 1, mt = w & 1;
    const int row  = blockIdx.x * 32 + mt * 16 + col;  // A-operand m = lane&15

    f32x4 acc[8];
    #pragma unroll
    for (int nt = 0; nt < 8; ++nt) acc[nt] = (f32x4){0.f, 0.f, 0.f, 0.f};

    const float* fxrow = fx + (size_t)row * H_;
    const short* wf = wtf + (size_t)mlp * 32768 + (size_t)l * 8;

    #pragma unroll
    for (int kt = 0; kt < 8; ++kt) {
        float4 a0 = *(const float4*)(fxrow + kt * 32 + quad * 8);
        float4 a1 = *(const float4*)(fxrow + kt * 32 + quad * 8 + 4);
        float af[8] = {a0.x, a0.y, a0.z, a0.w, a1.x, a1.y, a1.z, a1.w};
        bf16x8 ahi, alo;
        #pragma unroll
        for (int i = 0; i < 8; ++i) {
            union { float f; unsigned u; } c; c.f = af[i];
            unsigned hi = c.u >> 16;                       // truncate: lo holds residual
            ahi[i] = (short)hi;
            union { float f; unsigned u; } h2; h2.u = hi << 16;
            union { float f; unsigned u; } c2; c2.f = af[i] - h2.f;
            alo[i] = (short)(c2.u >> 16);
        }
        const short* base = wf + (size_t)kt * 4096;
        #pragma unroll
        for (int nt = 0; nt < 8; ++nt) {
            bf16x8 bf = *(const bf16x8*)(base + nt * 512);
            acc[nt] = __builtin_amdgcn_mfma_f32_16x16x32_bf16(ahi, bf, acc[nt], 0, 0, 0);
            acc[nt] = __builtin_amdgcn_mfma_f32_16x16x32_bf16(alo, bf, acc[nt], 0, 0, 0);
        }
    }

    // fp32 layer-2 epilogue
    const float* b1 = mlp ? cb1 : sb1;
    const float* w2 = mlp ? cw2 : sw2;
    const float  b2v = mlp ? cb2[0] : sb2[0];
    float p[4] = {0.f, 0.f, 0.f, 0.f};
    #pragma unroll
    for (int nt = 0; nt < 8; ++nt) {
        float b1c = b1[nt * 16 + col];
        float w2c = w2[nt * 16 + col];
        #pragma unroll
        for (int j = 0; j < 4; ++j)
            p[j] += fmaxf(acc[nt][j] + b1c, 0.f) * w2c;
    }
    #pragma unroll
    for (int off = 8; off >= 1; off >>= 1)
        #pragma unroll
        for (int j = 0; j < 4; ++j) p[j] += __shfl_down(p[j], off, 16);

    if (col == 0) {
        #pragma unroll
        for (int j = 0; j < 4; ++j) {
            int r = blockIdx.x * 32 + mt * 16 + quad * 4 + j;   // D row = quad*4+reg
            float v = p[j] + b2v;
            if (mlp == 0) sim[r] = v;
            else          conf[r] = 1.0f / (1.0f + expf(-v));
        }
    }
}

// ---------------------------------------------------------------------------
// Kernel 2: bucketed sums over param_x + softmax-denominator stats.
// Per block: batch b, 64-row chunk. LDS accumulators, atomicAdd flush.
// ---------------------------------------------------------------------------
__launch_bounds__(256)
__global__ void accum_kernel(const float* __restrict__ sim, const int* __restrict__ questions,
                             const float* __restrict__ px, float* __restrict__ ws_acc)
{
    const int b = blockIdx.x;
    const int chunk = blockIdx.y;         // 32 chunks of 64 rows
    const int tid = threadIdx.x;
    const int lane = tid & 63;            // p index
    const int g = tid >> 6;               // group 0..3
    __shared__ float accs[4][ACC_STRIDE];
    for (int s = tid; s < 4 * ACC_STRIDE; s += 256) ((float*)accs)[s] = 0.f;
    __syncthreads();

    const float* simb = sim + b * S_;
    const int*   qb   = questions + b * S_;
    const float* pxb  = px + (size_t)b * S_ * P_;

    float Treg = 0.f;
    const int i0 = chunk * 64 + g;
    for (int t = 0; t < 16; ++t) {
        int i = i0 + 4 * t;
        int qi = qb[i];                       // uniform across group -> broadcast
        float e = expf(simb[i]);
        float v = pxb[(size_t)i * P_ + lane]; // coalesced 256B per group
        Treg += v;
        accs[g][qi * 64 + lane]        += v;       // G_q
        accs[g][(20 + qi) * 64 + lane] += e * v;   // E_q
        if (lane == 0) {
            accs[g][2624 + qi] += e;               // W_q (denominator exp-sum)
            accs[g][2644 + qi] += 1.0f;            // n_q (group size)
        }
    }
    accs[g][2560 + lane] += Treg;                  // T
    __syncthreads();

    float* dst = ws_acc + (size_t)b * ACC_STRIDE;
    for (int s = tid; s < ACC_STRIDE; s += 256) {
        float sum = accs[0][s] + accs[1][s] + accs[2][s] + accs[3][s];
        atomicAdd(dst + s, sum);
    }
}

// ---------------------------------------------------------------------------
// Kernel 3: out = c*px + (1-c) * ((T - G_q + E_q) / denom_q), float4 per thread.
// denom_q = (S - n_q) + W_q computed inline from ws_acc.
// ---------------------------------------------------------------------------
__global__ void output_kernel(const float* __restrict__ px, const float* __restrict__ conf,
                              const int* __restrict__ questions, const float* __restrict__ ws_acc,
                              float* __restrict__ out)
{
    const int idx = blockIdx.x * 256 + threadIdx.x;  // float4 units, 262144 total
    const int row = idx >> 4;                        // b*S + s
    const int p4  = idx & 15;
    const int b   = row >> 11;                       // S = 2048
    const float c = conf[row];
    const int   q = questions[row];
    const float* accb = ws_acc + (size_t)b * ACC_STRIDE;
    const float4 T = *(const float4*)(accb + 2560 + p4 * 4);
    const float4 G = *(const float4*)(accb + q * 64 + p4 * 4);
    const float4 E = *(const float4*)(accb + (20 + q) * 64 + p4 * 4);
    const float denom = ((float)S_ - accb[2644 + q]) + accb[2624 + q];
    const float inv = 1.0f / denom;
    const float4 pv = ((const float4*)px)[idx];
    const float om = 1.0f - c;
    float4 o;
    o.x = c * pv.x + om * ((T.x - G.x + E.x) * inv);
    o.y = c * pv.y + om * ((T.y - G.y + E.y) * inv);
    o.z = c * pv.z + om * ((T.z - G.z + E.z) * inv);
    o.w = c * pv.w + om * ((T.w - G.w + E.w) * inv);
    ((float4*)out)[idx] = o;
}

// ---------------------------------------------------------------------------
extern "C" void kernel_launch(void* const* d_in, const int* in_sizes, int n_in,
                              void* d_out, int out_size, void* d_ws, size_t ws_size,
                              hipStream_t stream) {
    const float* fx  = (const float*)d_in[0];
    const float* px  = (const float*)d_in[1];
    const float* sw1 = (const float*)d_in[2];
    const float* sb1 = (const float*)d_in[3];
    const float* sw2 = (const float*)d_in[4];
    const float* sb2 = (const float*)d_in[5];
    const float* cw1 = (const float*)d_in[6];
    const float* cb1 = (const float*)d_in[7];
    const float* cw2 = (const float*)d_in[8];
    const float* cb2 = (const float*)d_in[9];
    const int* questions = (const int*)d_in[10];
    float* out = (float*)d_out;

    float* ws     = (float*)d_ws;
    float* sim    = ws + WS_SIM;
    float* conf   = ws + WS_CONF;
    float* ws_acc = ws + WS_ACC;
    short* wtf    = (short*)(ws + WS_WT);

    prep_kernel<<<32, 256, 0, stream>>>(sw1, cw1, wtf, ws_acc);
    mlp_mfma_kernel<<<M_ / 32, 256, 0, stream>>>(fx, wtf, sb1, sw2, sb2,
                                                 cb1, cw2, cb2, sim, conf);
    accum_kernel<<<dim3(B_, 32), 256, 0, stream>>>(sim, questions, px, ws_acc);
    output_kernel<<<(M_ * P_ / 4) / 256, 256, 0, stream>>>(px, conf, questions,
                                                           ws_acc, out);
}